// Round 1
// baseline (2205.632 us; speedup 1.0000x reference)
//
#include <hip/hip_runtime.h>
#include <hip/hip_bf16.h>

#define BB 2
#define CC 128
#define HH 128
#define WW 256
#define HWs (HH*WW)          // 32768
#define AUXC 133
#define KW 129               // rfft width
#define PI_F 3.14159265358979323846f

__device__ __forceinline__ ushort f2bf(float f) {
  uint u = __float_as_uint(f);
  u = (u + 0x7fffu + ((u >> 16) & 1u)) >> 16;
  return (ushort)u;
}

// ---- transpose weights (Cout, CinK) -> (CinK, Cout)
__global__ __launch_bounds__(256) void transpose_w_kernel(const float* __restrict__ w,
    float* __restrict__ wT, int Cout, int CinK) {
  int i = blockIdx.x * 256 + threadIdx.x;
  if (i >= Cout * CinK) return;
  int o = i / CinK, ck = i - o * CinK;
  wT[(size_t)ck * Cout + o] = w[i];
}

// ---- stage 1: real DFT along W: one row (256) -> 129 complex
__global__ __launch_bounds__(256) void dft_w_kernel(const float* __restrict__ x,
    float* __restrict__ fre, float* __restrict__ fim) {
  int row = blockIdx.x;              // (b*C+c)*H + h
  int t = threadIdx.x;
  __shared__ float sx[WW];
  __shared__ float twr[WW], twi[WW];
  sx[t] = x[(size_t)row * WW + t];
  float ang = (-2.0f * PI_F / 256.0f) * (float)t;
  twr[t] = cosf(ang); twi[t] = sinf(ang);
  __syncthreads();
  if (t < KW) {
    float re = 0.f, im = 0.f;
    int idx = 0;
    for (int w = 0; w < WW; w++) {
      float v = sx[w];
      re = fmaf(v, twr[idx], re);
      im = fmaf(v, twi[idx], im);
      idx = (idx + t) & 255;
    }
    fre[(size_t)row * KW + t] = re;
    fim[(size_t)row * KW + t] = im;
  }
}

// ---- stage 2: complex DFT along H (128), |.|, mean over C (atomic)
__global__ __launch_bounds__(256) void dft_h_kernel(const float* __restrict__ fre,
    const float* __restrict__ fim, float* __restrict__ fe) {
  int blk = blockIdx.x;
  int pair = blk % 65;
  int bc = blk / 65;                 // b*C + c
  int b = bc >> 7;
  int t = threadIdx.x;
  int kk = t >> 7, hh = t & 127;
  int k = pair * 2 + kk;
  __shared__ float cre[2][HH], cim[2][HH];
  __shared__ float twr[HH], twi[HH];
  if (t < HH) {
    float ang = (-2.0f * PI_F / 128.0f) * (float)t;
    twr[t] = cosf(ang); twi[t] = sinf(ang);
  }
  bool ok = (k < KW);
  if (ok) {
    cre[kk][hh] = fre[((size_t)bc * HH + hh) * KW + k];
    cim[kk][hh] = fim[((size_t)bc * HH + hh) * KW + k];
  }
  __syncthreads();
  if (ok) {
    float re = 0.f, im = 0.f;
    int idx = 0;
    for (int h = 0; h < HH; h++) {
      float tr = twr[idx], ti = twi[idx];
      float ar = cre[kk][h], ai = cim[kk][h];
      re = fmaf(ar, tr, re); re = fmaf(-ai, ti, re);
      im = fmaf(ar, ti, im); im = fmaf(ai, tr, im);
      idx = (idx + hh) & 127;
    }
    float mag = sqrtf(re * re + im * im);
    const float scale = 1.0f / (181.01933598375618f * 128.0f); // 1/sqrt(H*W)/C
    atomicAdd(&fe[((size_t)b * HH + hh) * KW + k], mag * scale);
  }
}

// ---- build aux = concat(x, erp coords, fe resized 129->256 along W)
__global__ __launch_bounds__(256) void build_aux_kernel(const float* __restrict__ x,
    const float* __restrict__ fe, float* __restrict__ aux) {
  int i = blockIdx.x * 256 + threadIdx.x;
  if (i >= BB * AUXC * HWs) return;
  int w = i & 255;
  int h = (i >> 8) & 127;
  int bc = i >> 15;                  // b*133 + ch
  int ch = bc % AUXC;
  int b = bc / AUXC;
  float v;
  if (ch < CC) {
    v = x[((size_t)b * CC + ch) * HWs + (h << 8) + w];
  } else if (ch < 132) {
    float theta = -PI_F + (float)w * (2.0f * PI_F / 255.0f);
    float phi   = -0.5f * PI_F + (float)h * (PI_F / 127.0f);
    v = (ch == 128) ? sinf(theta) : (ch == 129) ? cosf(theta)
      : (ch == 130) ? sinf(phi)   : cosf(phi);
  } else {
    float sx = ((float)w + 0.5f) * (129.0f / 256.0f) - 0.5f;
    float fx = floorf(sx);
    int x0 = (int)fx;
    float f = sx - fx;
    int x1 = x0 + 1;
    x0 = max(x0, 0); x1 = min(x1, 128);
    const float* fb = fe + ((size_t)b * HH + h) * KW;
    v = fb[x0] * (1.f - f) + fb[x1] * f;
  }
  aux[i] = v;
}

// ---- direct 3x3 conv, pad 1. wT layout: (CIN*9, Cout).
template<int CIN, int CHUNK>
__global__ __launch_bounds__(256) void conv3x3_kernel(
    const float* __restrict__ in, const float* __restrict__ wT,
    const float* __restrict__ bias, float* __restrict__ out,
    int Cout, int ngroups, int relu) {
  int gz = blockIdx.z;
  int b = gz / ngroups, grp = gz - b * ngroups;
  int oc0 = grp * CHUNK;
  int w0 = blockIdx.x * 32, h0 = blockIdx.y * 8;
  int tx = threadIdx.x & 31, ty = threadIdx.x >> 5;
  __shared__ float tile[10][34];
  float acc[CHUNK];
#pragma unroll
  for (int j = 0; j < CHUNK; j++) acc[j] = 0.f;
  const float* inb = in + (size_t)b * CIN * HWs;
  for (int c = 0; c < CIN; c++) {
    const float* inc = inb + (size_t)c * HWs;
    for (int i = threadIdx.x; i < 340; i += 256) {
      int iy = i / 34, ix = i - iy * 34;
      int gy = h0 + iy - 1, gx = w0 + ix - 1;
      float v = 0.f;
      if (gy >= 0 && gy < HH && gx >= 0 && gx < WW) v = inc[gy * WW + gx];
      tile[iy][ix] = v;
    }
    __syncthreads();
#pragma unroll
    for (int ky = 0; ky < 3; ky++)
#pragma unroll
      for (int kx = 0; kx < 3; kx++) {
        float v = tile[ty + ky][tx + kx];
        const float* wp = wT + (size_t)(c * 9 + ky * 3 + kx) * Cout + oc0;
#pragma unroll
        for (int j = 0; j < CHUNK; j++)
          acc[j] = fmaf(v, wp[j], acc[j]);
      }
    __syncthreads();
  }
  int oy = h0 + ty, ox = w0 + tx;
#pragma unroll
  for (int j = 0; j < CHUNK; j++) {
    int oc = oc0 + j;
    float r = acc[j] + bias[oc];
    if (relu) r = fmaxf(r, 0.f);
    out[((size_t)b * Cout + oc) * HWs + oy * WW + ox] = r;
  }
}

// ---- gate: 1x1 conv (66->1) + sigmoid
__global__ __launch_bounds__(256) void gate_kernel(const float* __restrict__ g,
    const float* __restrict__ w2, const float* __restrict__ b2,
    float* __restrict__ gate) {
  int i = blockIdx.x * 256 + threadIdx.x;
  if (i >= BB * HWs) return;
  int b = i >> 15;
  int p = i & 32767;
  const float* gb = g + (size_t)b * 66 * HWs + p;
  float s = b2[0];
  for (int c = 0; c < 66; c++) s = fmaf(gb[(size_t)c * HWs], w2[c], s);
  gate[i] = 1.f / (1.f + expf(-s));
}

// ---- fused: deform bilinear sample -> 1x1 conv (1152->128) -> gated blend
// block: 16 pixels (one h row segment), 256 threads
__global__ __launch_bounds__(256) void deform_out_kernel(
    const float* __restrict__ x, const float* __restrict__ offs,
    const float* __restrict__ wTdef, const float* __restrict__ def_b,
    const float* __restrict__ gate, float* __restrict__ out) {
  __shared__ ushort S[1152 * 16];    // bf16 sample tile, 36864 B
  __shared__ float wbuf[32 * 128];   // 16384 B
  __shared__ int   sidx[4][144];
  __shared__ float swgt[4][144];
  int t = threadIdx.x;
  int b = blockIdx.z, h = blockIdx.y, w0 = blockIdx.x * 16;
  const float* xb = x + (size_t)b * CC * HWs;
  if (t < 144) {
    int k = t >> 4, p = t & 15;
    int w = w0 + p;
    float ox = offs[((size_t)b * 18 + 2 * k) * HWs + h * WW + w];
    float oy = offs[((size_t)b * 18 + 2 * k + 1) * HWs + h * WW + w];
    float px = (float)w + ox, py = (float)h + oy;
    float fx = floorf(px), fy = floorf(py);
    int x0 = (int)fx, y0 = (int)fy;
    float wx1 = px - fx, wy1 = py - fy;
    float wx0 = 1.f - wx1, wy0 = 1.f - wy1;
    int x1 = x0 + 1, y1 = y0 + 1;
    bool vx0 = (x0 >= 0) && (x0 < WW), vx1 = (x1 >= 0) && (x1 < WW);
    bool vy0 = (y0 >= 0) && (y0 < HH), vy1 = (y1 >= 0) && (y1 < HH);
    int cx0 = min(max(x0, 0), WW - 1), cx1 = min(max(x1, 0), WW - 1);
    int cy0 = min(max(y0, 0), HH - 1), cy1 = min(max(y1, 0), HH - 1);
    sidx[0][t] = cy0 * WW + cx0; swgt[0][t] = (vx0 && vy0) ? wx0 * wy0 : 0.f;
    sidx[1][t] = cy0 * WW + cx1; swgt[1][t] = (vx1 && vy0) ? wx1 * wy0 : 0.f;
    sidx[2][t] = cy1 * WW + cx0; swgt[2][t] = (vx0 && vy1) ? wx0 * wy1 : 0.f;
    sidx[3][t] = cy1 * WW + cx1; swgt[3][t] = (vx1 && vy1) ? wx1 * wy1 : 0.f;
  }
  __syncthreads();
  {
    int p = t & 15, ckb = t >> 4;
    for (int i = 0; i < 72; i++) {
      int ck = ckb + (i << 4);
      int c = ck / 9, k = ck - c * 9;
      int kp = (k << 4) + p;
      const float* xc = xb + (size_t)c * HWs;
      float v = xc[sidx[0][kp]] * swgt[0][kp]
              + xc[sidx[1][kp]] * swgt[1][kp]
              + xc[sidx[2][kp]] * swgt[2][kp]
              + xc[sidx[3][kp]] * swgt[3][kp];
      S[(ck << 4) + p] = f2bf(v);
    }
  }
  float acc[4][2];
#pragma unroll
  for (int i = 0; i < 4; i++) { acc[i][0] = 0.f; acc[i][1] = 0.f; }
  int og = t >> 3, p2 = t & 7;
  for (int ckc = 0; ckc < 1152; ckc += 32) {
    __syncthreads();
    {
      const float4* src = (const float4*)(wTdef + (size_t)ckc * CC);
      float4* dst = (float4*)wbuf;
      for (int i = t; i < 1024; i += 256) dst[i] = src[i];
    }
    __syncthreads();
#pragma unroll
    for (int ck = 0; ck < 32; ck++) {
      uint u = *(const uint*)&S[((ckc + ck) << 4) + (p2 << 1)];
      float s0 = __uint_as_float(u << 16);
      float s1 = __uint_as_float(u & 0xffff0000u);
      float4 w4 = *(const float4*)&wbuf[(ck << 7) + (og << 2)];
      acc[0][0] = fmaf(w4.x, s0, acc[0][0]); acc[0][1] = fmaf(w4.x, s1, acc[0][1]);
      acc[1][0] = fmaf(w4.y, s0, acc[1][0]); acc[1][1] = fmaf(w4.y, s1, acc[1][1]);
      acc[2][0] = fmaf(w4.z, s0, acc[2][0]); acc[2][1] = fmaf(w4.z, s1, acc[2][1]);
      acc[3][0] = fmaf(w4.w, s0, acc[3][0]); acc[3][1] = fmaf(w4.w, s1, acc[3][1]);
    }
  }
  int wp0 = w0 + (p2 << 1);
  const float2 gv = *(const float2*)&gate[(size_t)b * HWs + h * WW + wp0];
#pragma unroll
  for (int i = 0; i < 4; i++) {
    int o = (og << 2) + i;
    size_t oidx = ((size_t)b * CC + o) * HWs + h * WW + wp0;
    float2 yb = *(const float2*)&out[oidx];
    float bd = def_b[o];
    float2 r;
    r.x = (1.f - gv.x) * yb.x + gv.x * (acc[i][0] + bd);
    r.y = (1.f - gv.y) * yb.y + gv.y * (acc[i][1] + bd);
    *(float2*)&out[oidx] = r;
  }
}

extern "C" void kernel_launch(void* const* d_in, const int* in_sizes, int n_in,
                              void* d_out, int out_size, void* d_ws, size_t ws_size,
                              hipStream_t stream) {
  const float* x        = (const float*)d_in[0];
  const float* offset_w = (const float*)d_in[1];
  const float* offset_b = (const float*)d_in[2];
  const float* gate_w1  = (const float*)d_in[3];
  const float* gate_b1  = (const float*)d_in[4];
  const float* gate_w2  = (const float*)d_in[5];
  const float* gate_b2  = (const float*)d_in[6];
  const float* base_w   = (const float*)d_in[7];
  const float* base_b   = (const float*)d_in[8];
  const float* def_w    = (const float*)d_in[9];
  const float* def_b    = (const float*)d_in[10];
  float* out = (float*)d_out;
  float* ws  = (float*)d_ws;

  float* fre     = ws;                    // 4,227,072 floats
  float* fim     = fre + 4227072;         // 4,227,072
  float* fe      = fim + 4227072;         //    33,024
  float* aux     = fe + 33024;            // 8,716,288
  float* offs    = aux + 8716288;         // 1,179,648
  float* gbuf    = offs + 1179648;        // 4,325,376
  float* gatebuf = gbuf + 4325376;        //    65,536
  float* wT_base = gatebuf + 65536;       //   147,456
  float* wT_def  = wT_base + 147456;      //   147,456
  float* wT_off  = wT_def + 147456;       //    21,546
  float* wT_g1   = wT_off + 21546;        //    79,002
  // total ~92.7 MB of d_ws

  hipMemsetAsync(fe, 0, 33024 * sizeof(float), stream);
  transpose_w_kernel<<<576, 256, 0, stream>>>(base_w, wT_base, 128, 1152);
  transpose_w_kernel<<<576, 256, 0, stream>>>(def_w, wT_def, 128, 1152);
  transpose_w_kernel<<<85, 256, 0, stream>>>(offset_w, wT_off, 18, 1197);
  transpose_w_kernel<<<309, 256, 0, stream>>>(gate_w1, wT_g1, 66, 1197);

  dft_w_kernel<<<BB * CC * HH, 256, 0, stream>>>(x, fre, fim);
  dft_h_kernel<<<BB * CC * 65, 256, 0, stream>>>(fre, fim, fe);
  build_aux_kernel<<<(BB * AUXC * HWs) / 256, 256, 0, stream>>>(x, fe, aux);

  conv3x3_kernel<AUXC, 18><<<dim3(8, 16, BB * 1), 256, 0, stream>>>(
      aux, wT_off, offset_b, offs, 18, 1, 0);
  conv3x3_kernel<AUXC, 22><<<dim3(8, 16, BB * 3), 256, 0, stream>>>(
      aux, wT_g1, gate_b1, gbuf, 66, 3, 1);
  gate_kernel<<<(BB * HWs) / 256, 256, 0, stream>>>(gbuf, gate_w2, gate_b2, gatebuf);

  conv3x3_kernel<CC, 32><<<dim3(8, 16, BB * 4), 256, 0, stream>>>(
      x, wT_base, base_b, out, 128, 4, 0);

  deform_out_kernel<<<dim3(16, 128, BB), 256, 0, stream>>>(
      x, offs, wT_def, def_b, gatebuf, out);
}

// Round 2
// 1044.998 us; speedup vs baseline: 2.1107x; 2.1107x over previous
//
#include <hip/hip_runtime.h>
#include <hip/hip_bf16.h>

#define BB 2
#define CC 128
#define HH 128
#define WW 256
#define HWs (HH*WW)          // 32768
#define AUXC 133
#define KW 129               // rfft width
#define PI_F 3.14159265358979323846f

typedef __attribute__((ext_vector_type(8))) short bf16x8;
typedef __attribute__((ext_vector_type(4))) float f32x4;

__device__ __forceinline__ ushort f2bf(float f) {
  uint u = __float_as_uint(f);
  u = (u + 0x7fffu + ((u >> 16) & 1u)) >> 16;
  return (ushort)u;
}
__device__ __forceinline__ float bf2f(ushort u) {
  return __uint_as_float(((uint)u) << 16);
}

// ---- x -> bf16 copy (for gathers)
__global__ __launch_bounds__(256) void xbf_kernel(const float* __restrict__ x,
    ushort* __restrict__ xb) {
  int i = blockIdx.x * 256 + threadIdx.x;
  float4 v = ((const float4*)x)[i];
  ushort4 o;
  o.x = f2bf(v.x); o.y = f2bf(v.y); o.z = f2bf(v.z); o.w = f2bf(v.w);
  ((ushort4*)xb)[i] = o;
}

// ---- pack [W_base | W_def] into MFMA A-fragment order, bf16
// frag index f = ((chunk*8 + mfrag)*4 + kf); element: apk[(f*64+lane)*8 + j]
// A[m][k]: m = mfrag*16 + (lane&15), c = kf*32 + (lane>>4)*8 + j, chunk=(part,tap)
__global__ __launch_bounds__(256) void pack_wfused_kernel(const float* __restrict__ bw,
    const float* __restrict__ dw, ushort* __restrict__ apk) {
  int gid = blockIdx.x * 256 + threadIdx.x;   // 144*256 = 36864 exact
  int lane = gid & 63;
  int kf = (gid >> 6) & 3;
  int mf = (gid >> 8) & 7;
  int chunk = gid >> 11;
  int part = chunk >= 9;
  int tap = part ? chunk - 9 : chunk;
  int m = mf * 16 + (lane & 15);
  int cb = kf * 32 + ((lane >> 4) << 3);
  const float* src = part ? dw : bw;
  ushort* dst = apk + (size_t)gid * 8;
#pragma unroll
  for (int j = 0; j < 8; ++j)
    dst[j] = f2bf(src[(size_t)m * 1152 + (size_t)(cb + j) * 9 + tap]);
}

// ---- pack [offset_w ; gate_w1 ; zeros] M=96, K=9 taps * 160 (133 real)
__global__ __launch_bounds__(256) void pack_waux_kernel(const float* __restrict__ ow,
    const float* __restrict__ gw, ushort* __restrict__ apk) {
  int gid = blockIdx.x * 256 + threadIdx.x;
  if (gid >= 17280) return;                   // 9*6*5*64
  int lane = gid & 63;
  int kf = (gid >> 6) % 5;
  int mf = (gid / 320) % 6;
  int tap = gid / 1920;
  int m = mf * 16 + (lane & 15);
  int cb = kf * 32 + ((lane >> 4) << 3);
#pragma unroll
  for (int j = 0; j < 8; ++j) {
    int c = cb + j;
    float v = 0.f;
    if (c < 133) {
      if (m < 18) v = ow[(size_t)m * 1197 + c * 9 + tap];
      else if (m < 84) v = gw[(size_t)(m - 18) * 1197 + c * 9 + tap];
    }
    apk[(size_t)gid * 8 + j] = f2bf(v);
  }
}

// ---- stage 1: real DFT along W. Block = 2 rows, thread k = t&127.
__global__ __launch_bounds__(256) void dft_w_kernel(const float* __restrict__ x,
    float* __restrict__ fre, float* __restrict__ fim) {
  int t = threadIdx.x;
  int r2 = blockIdx.x * 2;
  int rr = t >> 7, k = t & 127;
  __shared__ float sx[2][256];
  __shared__ float2 tw[256];
  sx[0][t] = x[(size_t)r2 * 256 + t];
  sx[1][t] = x[(size_t)(r2 + 1) * 256 + t];
  float ang = (-2.0f * PI_F / 256.0f) * (float)t;
  tw[t] = make_float2(cosf(ang), sinf(ang));
  __syncthreads();
  const float* sxr = sx[rr];
  float re = 0.f, im = 0.f;
  int idx = 0;
  for (int w = 0; w < 256; ++w) {
    float v = sxr[w];
    float2 c = tw[idx];
    re = fmaf(v, c.x, re);
    im = fmaf(v, c.y, im);
    idx = (idx + k) & 255;
  }
  size_t rowb = (size_t)(r2 + rr) * KW;
  fre[rowb + k] = re;
  fim[rowb + k] = im;
  if (k == 0) {           // Nyquist bin k=128: sum x[w]*(-1)^w
    float r128 = 0.f;
    for (int w = 0; w < 256; w += 2) r128 += sxr[w] - sxr[w + 1];
    fre[rowb + 128] = r128;
    fim[rowb + 128] = 0.f;
  }
}

// ---- stage 2: complex DFT along H (128), |.|, mean over C (atomic)
__global__ __launch_bounds__(256) void dft_h_kernel(const float* __restrict__ fre,
    const float* __restrict__ fim, float* __restrict__ fe) {
  int blk = blockIdx.x;
  int pair = blk % 65;
  int bc = blk / 65;
  int b = bc >> 7;
  int t = threadIdx.x;
  int kk = t >> 7, hh = t & 127;
  int k = pair * 2 + kk;
  __shared__ float2 cc[2][HH];
  __shared__ float2 tw[HH];
  if (t < HH) {
    float ang = (-2.0f * PI_F / 128.0f) * (float)t;
    tw[t] = make_float2(cosf(ang), sinf(ang));
  }
  bool ok = (k < KW);
  if (ok) {
    size_t base = ((size_t)bc * HH + hh) * KW + k;
    cc[kk][hh] = make_float2(fre[base], fim[base]);
  }
  __syncthreads();
  if (ok) {
    float re = 0.f, im = 0.f;
    int idx = 0;
    for (int h = 0; h < HH; ++h) {
      float2 a = cc[kk][h];
      float2 w = tw[idx];
      re = fmaf(a.x, w.x, re); re = fmaf(-a.y, w.y, re);
      im = fmaf(a.x, w.y, im); im = fmaf(a.y, w.x, im);
      idx = (idx + hh) & 127;
    }
    float mag = sqrtf(re * re + im * im);
    const float scale = 1.0f / (181.01933598375618f * 128.0f); // 1/sqrt(H*W)/C
    atomicAdd(&fe[((size_t)b * HH + hh) * KW + k], mag * scale);
  }
}

// ---- build aux = concat(x, erp coords, fe resized 129->256 along W)
__global__ __launch_bounds__(256) void build_aux_kernel(const float* __restrict__ x,
    const float* __restrict__ fe, float* __restrict__ aux) {
  int i = blockIdx.x * 256 + threadIdx.x;
  if (i >= BB * AUXC * HWs) return;
  int w = i & 255;
  int h = (i >> 8) & 127;
  int bc = i >> 15;
  int ch = bc % AUXC;
  int b = bc / AUXC;
  float v;
  if (ch < CC) {
    v = x[((size_t)b * CC + ch) * HWs + (h << 8) + w];
  } else if (ch < 132) {
    float theta = -PI_F + (float)w * (2.0f * PI_F / 255.0f);
    float phi   = -0.5f * PI_F + (float)h * (PI_F / 127.0f);
    v = (ch == 128) ? sinf(theta) : (ch == 129) ? cosf(theta)
      : (ch == 130) ? sinf(phi)   : cosf(phi);
  } else {
    float sx = ((float)w + 0.5f) * (129.0f / 256.0f) - 0.5f;
    float fx = floorf(sx);
    int x0 = (int)fx;
    float f = sx - fx;
    int x1 = x0 + 1;
    x0 = max(x0, 0); x1 = min(x1, 128);
    const float* fb = fe + ((size_t)b * HH + h) * KW;
    v = fb[x0] * (1.f - f) + fb[x1] * f;
  }
  aux[i] = v;
}

// ---- aux conv: offset(18)+gate1(66) as one MFMA GEMM, M=96, K=9*160
__global__ __launch_bounds__(256) void aux_conv_kernel(
    const float* __restrict__ aux, const ushort* __restrict__ apk,
    const float* __restrict__ offset_b, const float* __restrict__ gate_b1,
    float* __restrict__ offs, float* __restrict__ gbuf) {
  __shared__ ushort Bt[64][192];     // [p][k] XOR-swizzled, 24 KB
  int t = threadIdx.x;
  int bz = blockIdx.z, h = blockIdx.y, w0 = blockIdx.x * 64;
  int lane = t & 63, wid = t >> 6;
  int wm = wid >> 1, wn = wid & 1;
  f32x4 acc[3][2];
#pragma unroll
  for (int i = 0; i < 3; ++i) {
    acc[i][0] = (f32x4){0.f, 0.f, 0.f, 0.f};
    acc[i][1] = (f32x4){0.f, 0.f, 0.f, 0.f};
  }
  int p0 = wn * 32 + (lane & 15), p1 = p0 + 16;
  int q8 = (lane >> 4) << 3;
  const bf16x8* APK = (const bf16x8*)apk;
  for (int tap = 0; tap < 9; ++tap) {
    int ky = tap / 3 - 1, kx = tap % 3 - 1;
    __syncthreads();
    {
      int pp = t & 63, sw = (pp & 7) << 3;
      int gy = h + ky, gx = w0 + pp + kx;
      bool okp = (gy >= 0) && (gy < HH) && (gx >= 0) && (gx < WW);
      const float* ab = aux + ((size_t)bz * AUXC) * HWs;
      int gyx = gy * WW + gx;
      int c0 = wid * 2;
#pragma unroll
      for (int i = 0; i < 24; ++i) {
        int c = c0 + (i << 3);
        float v0 = (okp && c < 133) ? ab[(size_t)c * HWs + gyx] : 0.f;
        float v1 = (okp && (c + 1) < 133) ? ab[(size_t)(c + 1) * HWs + gyx] : 0.f;
        uint pk = (uint)f2bf(v0) | ((uint)f2bf(v1) << 16);
        *(uint*)&Bt[pp][c ^ sw] = pk;
      }
    }
    __syncthreads();
    size_t fb = ((size_t)tap * 6 + wm * 3) * 5;
#pragma unroll
    for (int kf = 0; kf < 5; ++kf) {
      int ko = kf * 32 + q8;
      bf16x8 b0 = *(const bf16x8*)&Bt[p0][ko ^ ((p0 & 7) << 3)];
      bf16x8 b1 = *(const bf16x8*)&Bt[p1][ko ^ ((p1 & 7) << 3)];
#pragma unroll
      for (int mf = 0; mf < 3; ++mf) {
        bf16x8 av = APK[(fb + (size_t)mf * 5 + kf) * 64 + lane];
        acc[mf][0] = __builtin_amdgcn_mfma_f32_16x16x32_bf16(av, b0, acc[mf][0], 0, 0, 0);
        acc[mf][1] = __builtin_amdgcn_mfma_f32_16x16x32_bf16(av, b1, acc[mf][1], 0, 0, 0);
      }
    }
  }
  int rq = (lane >> 4) << 2;
#pragma unroll
  for (int nf = 0; nf < 2; ++nf) {
    int p = wn * 32 + nf * 16 + (lane & 15);
    int w = w0 + p;
#pragma unroll
    for (int mf = 0; mf < 3; ++mf) {
      f32x4 a = acc[mf][nf];
      int ocb = wm * 48 + mf * 16 + rq;
#pragma unroll
      for (int r = 0; r < 4; ++r) {
        int oc = ocb + r;
        float v = a[r];
        if (oc < 18) {
          offs[((size_t)bz * 18 + oc) * HWs + h * WW + w] = v + offset_b[oc];
        } else if (oc < 84) {
          int o2 = oc - 18;
          gbuf[((size_t)bz * 66 + o2) * HWs + h * WW + w] = fmaxf(v + gate_b1[o2], 0.f);
        }
      }
    }
  }
}

// ---- gate: 1x1 conv (66->1) + sigmoid
__global__ __launch_bounds__(256) void gate_kernel(const float* __restrict__ g,
    const float* __restrict__ w2, const float* __restrict__ b2,
    float* __restrict__ gate) {
  int i = blockIdx.x * 256 + threadIdx.x;
  if (i >= BB * HWs) return;
  int b = i >> 15;
  int p = i & 32767;
  const float* gb = g + (size_t)b * 66 * HWs + p;
  float s = b2[0];
  for (int c = 0; c < 66; c++) s = fmaf(gb[(size_t)c * HWs], w2[c], s);
  gate[i] = 1.f / (1.f + expf(-s));
}

// ---- fused: (1-g)*conv3x3(x,Wb) + g*conv1x1(deform_sample(x),Wd), MFMA
// One K=2304 GEMM per 64-pixel tile; gate folded into B columns.
__global__ __launch_bounds__(256) void fused_out_kernel(
    const float* __restrict__ x, const ushort* __restrict__ xbf,
    const float* __restrict__ offs, const ushort* __restrict__ apk,
    const float* __restrict__ base_b, const float* __restrict__ def_b,
    const float* __restrict__ gate, float* __restrict__ out) {
  __shared__ ushort Bt[64][128];     // [p][k] XOR-swizzled, 16 KB
  __shared__ int   sidxS[4][576];
  __shared__ float swgtS[4][576];
  __shared__ float gvalS[64], goneS[64];
  __shared__ float bbS[128], bdS[128];
  int t = threadIdx.x;
  int bz = blockIdx.z, h = blockIdx.y, w0 = blockIdx.x * 64;
  int lane = t & 63, wid = t >> 6;
  int wm = wid >> 1, wn = wid & 1;

  // bilinear params for 9 taps x 64 px
  for (int e = t; e < 576; e += 256) {
    int tap = e >> 6, p = e & 63;
    int w = w0 + p;
    float ox = offs[((size_t)bz * 18 + 2 * tap) * HWs + h * WW + w];
    float oy = offs[((size_t)bz * 18 + 2 * tap + 1) * HWs + h * WW + w];
    float px = (float)w + ox, py = (float)h + oy;
    float fx = floorf(px), fy = floorf(py);
    int x0 = (int)fx, y0 = (int)fy;
    float wx1 = px - fx, wy1 = py - fy;
    float wx0 = 1.f - wx1, wy0 = 1.f - wy1;
    int x1 = x0 + 1, y1 = y0 + 1;
    bool vx0 = (x0 >= 0) && (x0 < WW), vx1 = (x1 >= 0) && (x1 < WW);
    bool vy0 = (y0 >= 0) && (y0 < HH), vy1 = (y1 >= 0) && (y1 < HH);
    int cx0 = min(max(x0, 0), WW - 1), cx1 = min(max(x1, 0), WW - 1);
    int cy0 = min(max(y0, 0), HH - 1), cy1 = min(max(y1, 0), HH - 1);
    sidxS[0][e] = cy0 * WW + cx0; swgtS[0][e] = (vx0 && vy0) ? wx0 * wy0 : 0.f;
    sidxS[1][e] = cy0 * WW + cx1; swgtS[1][e] = (vx1 && vy0) ? wx1 * wy0 : 0.f;
    sidxS[2][e] = cy1 * WW + cx0; swgtS[2][e] = (vx0 && vy1) ? wx0 * wy1 : 0.f;
    sidxS[3][e] = cy1 * WW + cx1; swgtS[3][e] = (vx1 && vy1) ? wx1 * wy1 : 0.f;
  }
  if (t < 64) {
    float g = gate[(size_t)bz * HWs + h * WW + w0 + t];
    gvalS[t] = g; goneS[t] = 1.f - g;
  }
  if (t >= 64 && t < 192) {
    int c = t - 64;
    bbS[c] = base_b[c];
    bdS[c] = def_b[c];
  }

  f32x4 acc[4][2];
#pragma unroll
  for (int i = 0; i < 4; ++i) {
    acc[i][0] = (f32x4){0.f, 0.f, 0.f, 0.f};
    acc[i][1] = (f32x4){0.f, 0.f, 0.f, 0.f};
  }
  int p0 = wn * 32 + (lane & 15), p1 = p0 + 16;
  int q8 = (lane >> 4) << 3;
  const bf16x8* APK = (const bf16x8*)apk;

  for (int chunk = 0; chunk < 18; ++chunk) {
    int part = chunk >= 9 ? 1 : 0;
    int tap = part ? chunk - 9 : chunk;
    __syncthreads();
    {
      int pp = t & 63, sw = (pp & 7) << 3;
      int c0 = wid * 2;
      if (!part) {
        int ky = tap / 3 - 1, kx = tap % 3 - 1;
        int gy = h + ky, gx = w0 + pp + kx;
        bool okp = (gy >= 0) && (gy < HH) && (gx >= 0) && (gx < WW);
        float gsc = goneS[pp];
        const float* xb = x + ((size_t)bz * CC) * HWs;
        int gyx = gy * WW + gx;
#pragma unroll
        for (int i = 0; i < 16; ++i) {
          int c = c0 + (i << 3);
          float v0 = okp ? xb[(size_t)c * HWs + gyx] : 0.f;
          float v1 = okp ? xb[(size_t)(c + 1) * HWs + gyx] : 0.f;
          uint pk = (uint)f2bf(v0 * gsc) | ((uint)f2bf(v1 * gsc) << 16);
          *(uint*)&Bt[pp][c ^ sw] = pk;
        }
      } else {
        int e = tap * 64 + pp;
        int i0 = sidxS[0][e], i1 = sidxS[1][e], i2 = sidxS[2][e], i3 = sidxS[3][e];
        float gsc = gvalS[pp];
        float g0 = swgtS[0][e] * gsc, g1 = swgtS[1][e] * gsc;
        float g2 = swgtS[2][e] * gsc, g3 = swgtS[3][e] * gsc;
        const ushort* xb = xbf + ((size_t)bz * CC) * HWs;
#pragma unroll 4
        for (int i = 0; i < 16; ++i) {
          int c = c0 + (i << 3);
          const ushort* xc = xb + ((size_t)c << 15);
          const ushort* xc1 = xc + HWs;
          float v0 = bf2f(xc[i0]) * g0 + bf2f(xc[i1]) * g1
                   + bf2f(xc[i2]) * g2 + bf2f(xc[i3]) * g3;
          float v1 = bf2f(xc1[i0]) * g0 + bf2f(xc1[i1]) * g1
                   + bf2f(xc1[i2]) * g2 + bf2f(xc1[i3]) * g3;
          uint pk = (uint)f2bf(v0) | ((uint)f2bf(v1) << 16);
          *(uint*)&Bt[pp][c ^ sw] = pk;
        }
      }
    }
    __syncthreads();
    size_t fb = ((size_t)chunk * 8 + wm * 4) * 4;
#pragma unroll
    for (int kf = 0; kf < 4; ++kf) {
      int ko = kf * 32 + q8;
      bf16x8 b0 = *(const bf16x8*)&Bt[p0][ko ^ ((p0 & 7) << 3)];
      bf16x8 b1 = *(const bf16x8*)&Bt[p1][ko ^ ((p1 & 7) << 3)];
#pragma unroll
      for (int mf = 0; mf < 4; ++mf) {
        bf16x8 av = APK[(fb + (size_t)mf * 4 + kf) * 64 + lane];
        acc[mf][0] = __builtin_amdgcn_mfma_f32_16x16x32_bf16(av, b0, acc[mf][0], 0, 0, 0);
        acc[mf][1] = __builtin_amdgcn_mfma_f32_16x16x32_bf16(av, b1, acc[mf][1], 0, 0, 0);
      }
    }
  }
  // epilogue: blended biases, direct store
  int rq = (lane >> 4) << 2;
#pragma unroll
  for (int nf = 0; nf < 2; ++nf) {
    int p = wn * 32 + nf * 16 + (lane & 15);
    float gv = gvalS[p], go = goneS[p];
    int w = w0 + p;
#pragma unroll
    for (int mf = 0; mf < 4; ++mf) {
      f32x4 a = acc[mf][nf];
      int ocb = wm * 64 + mf * 16 + rq;
#pragma unroll
      for (int r = 0; r < 4; ++r) {
        int oc = ocb + r;
        out[(((size_t)bz * CC + oc) << 15) + h * WW + w] = a[r] + go * bbS[oc] + gv * bdS[oc];
      }
    }
  }
}

extern "C" void kernel_launch(void* const* d_in, const int* in_sizes, int n_in,
                              void* d_out, int out_size, void* d_ws, size_t ws_size,
                              hipStream_t stream) {
  const float* x        = (const float*)d_in[0];
  const float* offset_w = (const float*)d_in[1];
  const float* offset_b = (const float*)d_in[2];
  const float* gate_w1  = (const float*)d_in[3];
  const float* gate_b1  = (const float*)d_in[4];
  const float* gate_w2  = (const float*)d_in[5];
  const float* gate_b2  = (const float*)d_in[6];
  const float* base_w   = (const float*)d_in[7];
  const float* base_b   = (const float*)d_in[8];
  const float* def_w    = (const float*)d_in[9];
  const float* def_b    = (const float*)d_in[10];
  float* out = (float*)d_out;
  float* ws  = (float*)d_ws;

  // region A: fre+fim during DFT, then aux (aliased; fre/fim dead by then)
  float* bigA    = ws;                      // 8,716,288 floats
  float* fre     = bigA;                    // 4,227,072
  float* fim     = bigA + 4227072;          // 4,227,072
  float* aux     = bigA;
  float* fe      = bigA + 8716288;          //    33,024
  float* offsb   = fe + 33024;              // 1,179,648
  float* gbuf    = offsb + 1179648;         // 4,325,376
  float* gatebuf = gbuf + 4325376;          //    65,536
  ushort* xbf    = (ushort*)(gatebuf + 65536);        // 8,388,608 ushort
  ushort* apkF   = (ushort*)((float*)(gatebuf + 65536) + 4194304); // 294,912 ushort
  ushort* apkA   = apkF + 294912;                     // 138,240 ushort
  // total ~71.5 MB

  hipMemsetAsync(fe, 0, 33024 * sizeof(float), stream);
  xbf_kernel<<<8192, 256, 0, stream>>>(x, xbf);
  pack_wfused_kernel<<<144, 256, 0, stream>>>(base_w, def_w, apkF);
  pack_waux_kernel<<<68, 256, 0, stream>>>(offset_w, gate_w1, apkA);

  dft_w_kernel<<<16384, 256, 0, stream>>>(x, fre, fim);
  dft_h_kernel<<<BB * CC * 65, 256, 0, stream>>>(fre, fim, fe);
  build_aux_kernel<<<(BB * AUXC * HWs) / 256, 256, 0, stream>>>(x, fe, aux);

  aux_conv_kernel<<<dim3(4, 128, BB), 256, 0, stream>>>(
      aux, apkA, offset_b, gate_b1, offsb, gbuf);
  gate_kernel<<<(BB * HWs) / 256, 256, 0, stream>>>(gbuf, gate_w2, gate_b2, gatebuf);

  fused_out_kernel<<<dim3(4, 128, BB), 256, 0, stream>>>(
      x, xbf, offsb, apkF, base_b, def_b, gatebuf, out);
}

// Round 3
// 261.759 us; speedup vs baseline: 8.4262x; 3.9922x over previous
//
#include <hip/hip_runtime.h>
#include <hip/hip_bf16.h>

#define BB 2
#define CC 128
#define HH 128
#define WW 256
#define HWs (HH*WW)          // 32768
#define PI_F 3.14159265358979323846f

typedef __attribute__((ext_vector_type(8))) short bf16x8;
typedef __attribute__((ext_vector_type(8))) unsigned short u16x8;
typedef __attribute__((ext_vector_type(4))) float f32x4;

__device__ __forceinline__ ushort f2bf(float f) {   // RNE
  uint u = __float_as_uint(f);
  u = (u + 0x7fffu + ((u >> 16) & 1u)) >> 16;
  return (ushort)u;
}
__device__ __forceinline__ uint f2bf_fast(float f) { // round-half-up
  return (__float_as_uint(f) + 0x8000u) >> 16;
}
__device__ __forceinline__ float bf2f(ushort u) {
  return __uint_as_float(((uint)u) << 16);
}

// ---- pack [W_base | W_def] into MFMA A-fragment order, bf16
// frag f = (chunk*8 + mf)*4 + kf; elem apk[(f*64+lane)*8+j]
// A[m][c]: m = mf*16+(lane&15), c = kf*32+(lane>>4)*8+j, chunk = (part,tap)
__global__ __launch_bounds__(256) void pack_wfused_kernel(const float* __restrict__ bw,
    const float* __restrict__ dw, ushort* __restrict__ apk) {
  int gid = blockIdx.x * 256 + threadIdx.x;   // 144*256 = 36864
  int lane = gid & 63;
  int kf = (gid >> 6) & 3;
  int mf = (gid >> 8) & 7;
  int chunk = gid >> 11;
  int part = chunk >= 9;
  int tap = part ? chunk - 9 : chunk;
  int m = mf * 16 + (lane & 15);
  int cb = kf * 32 + ((lane >> 4) << 3);
  const float* src = part ? dw : bw;
  ushort* dst = apk + (size_t)gid * 8;
#pragma unroll
  for (int j = 0; j < 8; ++j)
    dst[j] = f2bf(src[(size_t)m * 1152 + (size_t)(cb + j) * 9 + tap]);
}

// ---- pack [offset_w ; gate_w1 ; zeros] M=96, K=9 taps * 160 (133 real)
__global__ __launch_bounds__(256) void pack_waux_kernel(const float* __restrict__ ow,
    const float* __restrict__ gw, ushort* __restrict__ apk) {
  int gid = blockIdx.x * 256 + threadIdx.x;
  if (gid >= 17280) return;                   // 9*6*5*64
  int lane = gid & 63;
  int kf = (gid >> 6) % 5;
  int mf = (gid / 320) % 6;
  int tap = gid / 1920;
  int m = mf * 16 + (lane & 15);
  int cb = kf * 32 + ((lane >> 4) << 3);
#pragma unroll
  for (int j = 0; j < 8; ++j) {
    int c = cb + j;
    float v = 0.f;
    if (c < 133) {
      if (m < 18) v = ow[(size_t)m * 1197 + c * 9 + tap];
      else if (m < 84) v = gw[(size_t)(m - 18) * 1197 + c * 9 + tap];
    }
    apk[(size_t)gid * 8 + j] = f2bf(v);
  }
}

// ---- twiddle packs. a1: M=320 (129 cos, 129 -sin, pad), K=256.
//      a2: M=256 (128 [cos|sin], 128 [-sin|cos]), K=256.
__global__ __launch_bounds__(256) void pack_tw_kernel(ushort* __restrict__ a1,
    ushort* __restrict__ a2) {
  int gid = blockIdx.x * 256 + threadIdx.x;
  if (gid < 10240) {
    int lane = gid & 63, kf = (gid >> 6) & 7, mf = gid >> 9;
    int m = mf * 16 + (lane & 15);
    int kk0 = kf * 32 + ((lane >> 4) << 3);
#pragma unroll
    for (int j = 0; j < 8; ++j) {
      int kk = kk0 + j;
      float v = 0.f;
      if (m < 129)      { int tt = (m * kk) & 255;        v =  cosf(tt * (PI_F / 128.f)); }
      else if (m < 258) { int tt = ((m - 129) * kk) & 255; v = -sinf(tt * (PI_F / 128.f)); }
      a1[(size_t)gid * 8 + j] = f2bf(v);
    }
  } else if (gid < 18432) {
    int q = gid - 10240;
    int lane = q & 63, kf = (q >> 6) & 7, mf = q >> 9;
    int m = mf * 16 + (lane & 15);
    int g = m & 127;
    int kk0 = kf * 32 + ((lane >> 4) << 3);
#pragma unroll
    for (int j = 0; j < 8; ++j) {
      int kk = kk0 + j;
      int h2 = kk & 127;
      int tt = (g * h2) & 127;
      float ang = tt * (PI_F / 64.f);
      float v = (m < 128) ? ((kk < 128) ? cosf(ang) : sinf(ang))
                          : ((kk < 128) ? -sinf(ang) : cosf(ang));
      a2[(size_t)q * 8 + j] = f2bf(v);
    }
  }
}

// ---- x (NCHW f32) -> xt (NHWC bf16)
__global__ __launch_bounds__(256) void xt_kernel(const float* __restrict__ x,
    ushort* __restrict__ xt) {
  __shared__ ushort sT[64][128];
  int blk = blockIdx.x;                 // b*128 + h
  int b = blk >> 7, h = blk & 127;
  int t = threadIdx.x;
  const float* xb = x + ((size_t)b * CC * HH + h) * WW;
  ushort* ob = xt + (((size_t)b * HH + h) * WW) * 128;
  for (int wt = 0; wt < 4; ++wt) {
    __syncthreads();
    {
      int w = t & 63;
      int sw = (w & 7) << 3;
#pragma unroll
      for (int it = 0; it < 4; ++it) {
        int oct = (t >> 6) + it * 4;
        u16x8 v;
#pragma unroll
        for (int j = 0; j < 8; ++j)
          v[j] = f2bf(xb[(size_t)(oct * 8 + j) * HWs + wt * 64 + w]);
        *(u16x8*)&sT[w][(oct << 3) ^ sw] = v;
      }
    }
    __syncthreads();
#pragma unroll
    for (int it = 0; it < 4; ++it) {
      int u = t + it * 256;
      int w = u >> 4, oct = u & 15;
      u16x8 v = *(const u16x8*)&sT[w][(oct << 3) ^ ((w & 7) << 3)];
      *(u16x8*)&ob[(size_t)(wt * 64 + w) * 128 + oct * 8] = v;
    }
  }
}

// ---- DFT stage 1 (along W), MFMA: C[m=k(re/im)][n=h] = sum_w A1[m][w]*x[h][w]
__global__ __launch_bounds__(256) void dft1_kernel(const float* __restrict__ x,
    const ushort* __restrict__ a1pk, ushort* __restrict__ F1) {
  int bc = blockIdx.x;
  int t = threadIdx.x, lane = t & 63, wv = t >> 6;
  int q8 = (lane >> 4) << 3, rq = (lane >> 4) << 2;
  const bf16x8* APK = (const bf16x8*)a1pk;
  ushort* f1b = F1 + (size_t)bc * 36864;
  for (int nh = 0; nh < 2; ++nh) {
    f32x4 acc[5][4];
#pragma unroll
    for (int i = 0; i < 5; ++i)
#pragma unroll
      for (int n = 0; n < 4; ++n) acc[i][n] = (f32x4){0.f, 0.f, 0.f, 0.f};
    for (int kf = 0; kf < 8; ++kf) {
      bf16x8 av[5];
#pragma unroll
      for (int i = 0; i < 5; ++i)
        av[i] = APK[(size_t)((wv * 5 + i) * 8 + kf) * 64 + lane];
#pragma unroll
      for (int n2 = 0; n2 < 4; ++n2) {
        int nf = nh * 4 + n2;
        int hh = nf * 16 + (lane & 15);
        const float* xp = x + (((size_t)bc * HH + hh) << 8) + kf * 32 + q8;
        float4 xa = *(const float4*)xp;
        float4 xb4 = *(const float4*)(xp + 4);
        bf16x8 bv;
        bv[0] = (short)f2bf(xa.x); bv[1] = (short)f2bf(xa.y);
        bv[2] = (short)f2bf(xa.z); bv[3] = (short)f2bf(xa.w);
        bv[4] = (short)f2bf(xb4.x); bv[5] = (short)f2bf(xb4.y);
        bv[6] = (short)f2bf(xb4.z); bv[7] = (short)f2bf(xb4.w);
#pragma unroll
        for (int i = 0; i < 5; ++i)
          acc[i][n2] = __builtin_amdgcn_mfma_f32_16x16x32_bf16(av[i], bv, acc[i][n2], 0, 0, 0);
      }
    }
#pragma unroll
    for (int n2 = 0; n2 < 4; ++n2) {
      int hh = (nh * 4 + n2) * 16 + (lane & 15);
#pragma unroll
      for (int i = 0; i < 5; ++i) {
#pragma unroll
        for (int r = 0; r < 4; ++r) {
          int m = (wv * 5 + i) * 16 + rq + r;
          if (m < 258) {
            int sel = m >= 129;
            int k = sel ? m - 129 : m;
            f1b[(size_t)k * 256 + sel * 128 + hh] = f2bf(acc[i][n2][r]);
          }
        }
      }
    }
  }
}

// ---- DFT stage 2 (along H) + magnitude. M=256 (Yr rows 0-127, Yi 128-255).
__global__ __launch_bounds__(256) void dft2_kernel(const ushort* __restrict__ F1,
    const ushort* __restrict__ a2pk, float* __restrict__ magbuf) {
  int bc = blockIdx.x;
  int t = threadIdx.x, lane = t & 63, wv = t >> 6;
  int q8 = (lane >> 4) << 3, rq = (lane >> 4) << 2;
  const bf16x8* APK = (const bf16x8*)a2pk;
  const ushort* f1b = F1 + (size_t)bc * 36864;
  float* mb = magbuf + (size_t)bc * 18432;
  for (int ng = 0; ng < 3; ++ng) {
    f32x4 acc[4][3];
#pragma unroll
    for (int i = 0; i < 4; ++i)
#pragma unroll
      for (int n = 0; n < 3; ++n) acc[i][n] = (f32x4){0.f, 0.f, 0.f, 0.f};
    for (int kf = 0; kf < 8; ++kf) {
      bf16x8 av[4];
#pragma unroll
      for (int i = 0; i < 4; ++i) {
        int mf = (i < 2) ? (2 * wv + i) : (2 * wv + (i - 2) + 8);
        av[i] = APK[(size_t)(mf * 8 + kf) * 64 + lane];
      }
#pragma unroll
      for (int n2 = 0; n2 < 3; ++n2) {
        int nf = ng * 3 + n2;
        int krow = nf * 16 + (lane & 15);
        bf16x8 bv = *(const bf16x8*)&f1b[(size_t)krow * 256 + kf * 32 + q8];
#pragma unroll
        for (int i = 0; i < 4; ++i)
          acc[i][n2] = __builtin_amdgcn_mfma_f32_16x16x32_bf16(av[i], bv, acc[i][n2], 0, 0, 0);
      }
    }
#pragma unroll
    for (int n2 = 0; n2 < 3; ++n2) {
      int k = (ng * 3 + n2) * 16 + (lane & 15);
      if (k < 129) {
#pragma unroll
        for (int pr = 0; pr < 2; ++pr) {
#pragma unroll
          for (int r = 0; r < 4; ++r) {
            int g = (2 * wv + pr) * 16 + rq + r;
            float vr = acc[pr][n2][r], vi = acc[pr + 2][n2][r];
            mb[(size_t)g * 144 + k] = sqrtf(vr * vr + vi * vi);
          }
        }
      }
    }
  }
}

// ---- reduce magnitude over channels -> fe[b][g][129]
__global__ __launch_bounds__(256) void fe_reduce_kernel(const float* __restrict__ magbuf,
    float* __restrict__ fe) {
  int i = blockIdx.x * 256 + threadIdx.x;   // 36864
  if (i >= 36864) return;
  int k = i % 144;
  int gb = i / 144;
  int g = gb & 127, b = gb >> 7;
  if (k >= 129) return;
  const float* mp = magbuf + (size_t)b * 128 * 18432 + (size_t)g * 144 + k;
  float s = 0.f;
  for (int c = 0; c < 128; ++c) s += mp[(size_t)c * 18432];
  fe[((size_t)b * 128 + g) * 129 + k] = s * (1.0f / (181.01933598375618f * 128.0f));
}

// ---- aux conv (offset 18ch + gate1 66ch) + gate 1x1 + sigmoid, fused. MFMA.
__global__ __launch_bounds__(256) void aux_conv_kernel(
    const ushort* __restrict__ xt, const float* __restrict__ fe,
    const ushort* __restrict__ apk,
    const float* __restrict__ offset_b, const float* __restrict__ gate_b1,
    const float* __restrict__ w2, const float* __restrict__ b2,
    float* __restrict__ offs, float* __restrict__ gate) {
  __shared__ ushort Bt[64][168];
  __shared__ float gld[66][64];
  __shared__ float2 thS[66];
  __shared__ float2 phS[3];
  __shared__ float feS[3][66];
  int t = threadIdx.x;
  int bid = blockIdx.x;
  int lin = (bid & 7) * 128 + (bid >> 3);
  int bz = lin >> 9;
  int rest = lin & 511;
  int h = rest >> 2, w0 = (rest & 3) << 6;
  int lane = t & 63, wid = t >> 6;
  int wm = wid >> 1, wn = wid & 1;
  int q8 = (lane >> 4) << 3, rq = (lane >> 4) << 2;

  if (t < 66) {
    float th = -PI_F + (float)(w0 + t - 1) * (2.0f * PI_F / 255.0f);
    thS[t] = make_float2(sinf(th), cosf(th));
  }
  if (t < 3) {
    float ph = -0.5f * PI_F + (float)(h + t - 1) * (PI_F / 127.0f);
    phS[t] = make_float2(sinf(ph), cosf(ph));
  }
  if (t < 198) {
    int gyi = t / 66, gxi = t % 66;
    int gy = h + gyi - 1, gx = w0 + gxi - 1;
    float v = 0.f;
    if (gy >= 0 && gy < HH && gx >= 0 && gx < WW) {
      float sxc = ((float)gx + 0.5f) * (129.0f / 256.0f) - 0.5f;
      float fx = floorf(sxc);
      int x0 = (int)fx;
      float fr = sxc - fx;
      int x1 = min(x0 + 1, 128);
      x0 = max(x0, 0);
      const float* fb = fe + ((size_t)bz * 128 + gy) * 129;
      v = fb[x0] * (1.f - fr) + fb[x1] * fr;
    }
    feS[gyi][gxi] = v;
  }

  f32x4 acc[3][2];
#pragma unroll
  for (int i = 0; i < 3; ++i) {
    acc[i][0] = (f32x4){0.f, 0.f, 0.f, 0.f};
    acc[i][1] = (f32x4){0.f, 0.f, 0.f, 0.f};
  }
  int p0 = wn * 32 + (lane & 15), p1 = p0 + 16;
  const bf16x8* APK = (const bf16x8*)apk;
  const ushort* xtb = xt + (size_t)bz * 4194304;

  for (int tap = 0; tap < 9; ++tap) {
    int ky = tap / 3 - 1, kx = tap % 3 - 1;
    int gy = h + ky;
    __syncthreads();
    for (int u = t; u < 1280; u += 256) {
      int oct = u >> 6, p = u & 63;
      int gx = w0 + p + kx;
      bool okp = (gy >= 0) && (gy < HH) && ((unsigned)gx < 256u);
      u16x8 v = (u16x8){0, 0, 0, 0, 0, 0, 0, 0};
      if (oct < 16) {
        if (okp) v = *(const u16x8*)&xtb[((((size_t)gy << 8) + gx) << 7) + (oct << 3)];
      } else if (oct == 16) {
        if (okp) {
          float2 tc = thS[p + kx + 1];
          float2 pc = phS[ky + 1];
          float fv = feS[ky + 1][p + kx + 1];
          v[0] = f2bf(tc.x); v[1] = f2bf(tc.y);
          v[2] = f2bf(pc.x); v[3] = f2bf(pc.y);
          v[4] = f2bf(fv);
        }
      }
      *(u16x8*)&Bt[p][oct << 3] = v;
    }
    __syncthreads();
    int fb = (tap * 6 + wm * 3) * 5;
#pragma unroll
    for (int kf = 0; kf < 5; ++kf) {
      int ko = kf * 32 + q8;
      bf16x8 b0 = *(const bf16x8*)&Bt[p0][ko];
      bf16x8 b1 = *(const bf16x8*)&Bt[p1][ko];
#pragma unroll
      for (int mf = 0; mf < 3; ++mf) {
        bf16x8 av = APK[(size_t)(fb + mf * 5 + kf) * 64 + lane];
        acc[mf][0] = __builtin_amdgcn_mfma_f32_16x16x32_bf16(av, b0, acc[mf][0], 0, 0, 0);
        acc[mf][1] = __builtin_amdgcn_mfma_f32_16x16x32_bf16(av, b1, acc[mf][1], 0, 0, 0);
      }
    }
  }
#pragma unroll
  for (int nf = 0; nf < 2; ++nf) {
    int p = wn * 32 + nf * 16 + (lane & 15);
    int w = w0 + p;
#pragma unroll
    for (int mf = 0; mf < 3; ++mf) {
#pragma unroll
      for (int r = 0; r < 4; ++r) {
        int oc = wm * 48 + mf * 16 + rq + r;
        float v = acc[mf][nf][r];
        if (oc < 18) {
          offs[((size_t)bz * 18 + oc) * HWs + h * WW + w] = v + offset_b[oc];
        } else if (oc < 84) {
          gld[oc - 18][p] = fmaxf(v + gate_b1[oc - 18], 0.f);
        }
      }
    }
  }
  __syncthreads();
  if (t < 64) {
    float s = b2[0];
    for (int c = 0; c < 66; ++c) s = fmaf(gld[c][t], w2[c], s);
    gate[(size_t)bz * HWs + h * WW + w0 + t] = 1.f / (1.f + expf(-s));
  }
}

// ---- fused output: split-acc MFMA GEMM over K=2304 (9 base taps + 9 deform taps)
__global__ __launch_bounds__(256) void fused_out_kernel(
    const ushort* __restrict__ xt, const float* __restrict__ offs,
    const ushort* __restrict__ apk,
    const float* __restrict__ base_b, const float* __restrict__ def_b,
    const float* __restrict__ gate, float* __restrict__ out) {
  __shared__ ushort Bt[64][136];
  __shared__ int   sidxS[4][576];
  __shared__ float swgtS[4][576];
  __shared__ float gvS[64];
  __shared__ float bbS[128], bdS[128];
  int t = threadIdx.x;
  int bid = blockIdx.x;
  int lin = (bid & 7) * 128 + (bid >> 3);
  int bz = lin >> 9;
  int rest = lin & 511;
  int h = rest >> 2, w0 = (rest & 3) << 6;
  int lane = t & 63, wid = t >> 6;
  int q8 = (lane >> 4) << 3, rq = (lane >> 4) << 2;

  for (int e = t; e < 576; e += 256) {
    int tap = e >> 6, p = e & 63;
    int w = w0 + p;
    float ox = offs[((size_t)bz * 18 + 2 * tap) * HWs + h * WW + w];
    float oy = offs[((size_t)bz * 18 + 2 * tap + 1) * HWs + h * WW + w];
    float px = (float)w + ox, py = (float)h + oy;
    float fx = floorf(px), fy = floorf(py);
    int x0 = (int)fx, y0 = (int)fy;
    float wx1 = px - fx, wy1 = py - fy;
    float wx0 = 1.f - wx1, wy0 = 1.f - wy1;
    int x1 = x0 + 1, y1 = y0 + 1;
    bool vx0 = (x0 >= 0) && (x0 < WW), vx1 = (x1 >= 0) && (x1 < WW);
    bool vy0 = (y0 >= 0) && (y0 < HH), vy1 = (y1 >= 0) && (y1 < HH);
    int cx0 = min(max(x0, 0), WW - 1), cx1 = min(max(x1, 0), WW - 1);
    int cy0 = min(max(y0, 0), HH - 1), cy1 = min(max(y1, 0), HH - 1);
    sidxS[0][e] = ((cy0 << 8) + cx0) << 7; swgtS[0][e] = (vx0 && vy0) ? wx0 * wy0 : 0.f;
    sidxS[1][e] = ((cy0 << 8) + cx1) << 7; swgtS[1][e] = (vx1 && vy0) ? wx1 * wy0 : 0.f;
    sidxS[2][e] = ((cy1 << 8) + cx0) << 7; swgtS[2][e] = (vx0 && vy1) ? wx0 * wy1 : 0.f;
    sidxS[3][e] = ((cy1 << 8) + cx1) << 7; swgtS[3][e] = (vx1 && vy1) ? wx1 * wy1 : 0.f;
  }
  if (t < 64) gvS[t] = gate[(size_t)bz * HWs + h * WW + w0 + t];
  if (t >= 64 && t < 192) {
    int c = t - 64;
    bbS[c] = base_b[c];
    bdS[c] = def_b[c];
  }

  f32x4 accB[2][4], accD[2][4];
#pragma unroll
  for (int i = 0; i < 2; ++i)
#pragma unroll
    for (int n = 0; n < 4; ++n) {
      accB[i][n] = (f32x4){0.f, 0.f, 0.f, 0.f};
      accD[i][n] = (f32x4){0.f, 0.f, 0.f, 0.f};
    }
  const bf16x8* APK = (const bf16x8*)apk;
  const ushort* xtb = xt + (size_t)bz * 4194304;

  for (int chunk = 0; chunk < 18; ++chunk) {
    __syncthreads();
    if (chunk < 9) {
      int ky = chunk / 3 - 1, kx = chunk % 3 - 1;
      int gy = h + ky;
      bool oky = (gy >= 0) && (gy < HH);
#pragma unroll
      for (int it = 0; it < 4; ++it) {
        int u = t + it * 256;
        int oct = u >> 6, p = u & 63;
        int gx = w0 + p + kx;
        u16x8 v = (u16x8){0, 0, 0, 0, 0, 0, 0, 0};
        if (oky && ((unsigned)gx < 256u))
          v = *(const u16x8*)&xtb[((((size_t)gy << 8) + gx) << 7) + (oct << 3)];
        *(u16x8*)&Bt[p][oct << 3] = v;
      }
    } else {
      int e0 = (chunk - 9) << 6;
#pragma unroll
      for (int it = 0; it < 4; ++it) {
        int u = t + it * 256;
        int oct = u >> 6, p = u & 63;
        int e = e0 + p, o8 = oct << 3;
        u16x8 a0 = *(const u16x8*)&xtb[sidxS[0][e] + o8];
        u16x8 a1 = *(const u16x8*)&xtb[sidxS[1][e] + o8];
        u16x8 a2 = *(const u16x8*)&xtb[sidxS[2][e] + o8];
        u16x8 a3 = *(const u16x8*)&xtb[sidxS[3][e] + o8];
        float g0 = swgtS[0][e], g1 = swgtS[1][e], g2 = swgtS[2][e], g3 = swgtS[3][e];
        uint pk[4];
#pragma unroll
        for (int i = 0; i < 4; ++i) {
          float f0 = bf2f(a0[2*i]) * g0 + bf2f(a1[2*i]) * g1
                   + bf2f(a2[2*i]) * g2 + bf2f(a3[2*i]) * g3;
          float f1 = bf2f(a0[2*i+1]) * g0 + bf2f(a1[2*i+1]) * g1
                   + bf2f(a2[2*i+1]) * g2 + bf2f(a3[2*i+1]) * g3;
          pk[i] = f2bf_fast(f0) | (f2bf_fast(f1) << 16);
        }
        *(uint4*)&Bt[p][o8] = make_uint4(pk[0], pk[1], pk[2], pk[3]);
      }
    }
    __syncthreads();
    int fb = (chunk * 8 + wid * 2) * 4;
#pragma unroll
    for (int kf = 0; kf < 4; ++kf) {
      int ko = kf * 32 + q8;
      bf16x8 a0 = APK[(size_t)(fb + kf) * 64 + lane];
      bf16x8 a1 = APK[(size_t)(fb + 4 + kf) * 64 + lane];
#pragma unroll
      for (int nf = 0; nf < 4; ++nf) {
        bf16x8 bv = *(const bf16x8*)&Bt[nf * 16 + (lane & 15)][ko];
        if (chunk < 9) {
          accB[0][nf] = __builtin_amdgcn_mfma_f32_16x16x32_bf16(a0, bv, accB[0][nf], 0, 0, 0);
          accB[1][nf] = __builtin_amdgcn_mfma_f32_16x16x32_bf16(a1, bv, accB[1][nf], 0, 0, 0);
        } else {
          accD[0][nf] = __builtin_amdgcn_mfma_f32_16x16x32_bf16(a0, bv, accD[0][nf], 0, 0, 0);
          accD[1][nf] = __builtin_amdgcn_mfma_f32_16x16x32_bf16(a1, bv, accD[1][nf], 0, 0, 0);
        }
      }
    }
  }
#pragma unroll
  for (int nf = 0; nf < 4; ++nf) {
    int p = nf * 16 + (lane & 15);
    float gv = gvS[p], go = 1.f - gv;
    int w = w0 + p;
#pragma unroll
    for (int i = 0; i < 2; ++i) {
      int ocb = wid * 32 + i * 16 + rq;
#pragma unroll
      for (int r = 0; r < 4; ++r) {
        int oc = ocb + r;
        out[(((size_t)bz * CC + oc) << 15) + h * WW + w] =
            go * (accB[i][nf][r] + bbS[oc]) + gv * (accD[i][nf][r] + bdS[oc]);
      }
    }
  }
}

extern "C" void kernel_launch(void* const* d_in, const int* in_sizes, int n_in,
                              void* d_out, int out_size, void* d_ws, size_t ws_size,
                              hipStream_t stream) {
  const float* x        = (const float*)d_in[0];
  const float* offset_w = (const float*)d_in[1];
  const float* offset_b = (const float*)d_in[2];
  const float* gate_w1  = (const float*)d_in[3];
  const float* gate_b1  = (const float*)d_in[4];
  const float* gate_w2  = (const float*)d_in[5];
  const float* gate_b2  = (const float*)d_in[6];
  const float* base_w   = (const float*)d_in[7];
  const float* base_b   = (const float*)d_in[8];
  const float* def_w    = (const float*)d_in[9];
  const float* def_b    = (const float*)d_in[10];
  float* out = (float*)d_out;
  float* ws  = (float*)d_ws;

  float* offsb   = ws;                          // 1,179,648 f
  float* gatebuf = offsb + 1179648;             //    65,536 f
  float* fe      = gatebuf + 65536;             //    33,024 f
  float* magbuf  = fe + 33024;                  // 4,718,592 f
  ushort* xt     = (ushort*)(magbuf + 4718592); // 16,777,216 ush
  ushort* F1     = xt + 16777216;               //  9,437,184 ush
  ushort* a1pk   = F1 + 9437184;                //     81,920 ush
  ushort* a2pk   = a1pk + 81920;                //     65,536 ush
  ushort* apkF   = a2pk + 65536;                //    294,912 ush
  ushort* apkA   = apkF + 294912;               //    138,240 ush
  // total ~77.6 MB

  pack_wfused_kernel<<<144, 256, 0, stream>>>(base_w, def_w, apkF);
  pack_waux_kernel<<<68, 256, 0, stream>>>(offset_w, gate_w1, apkA);
  pack_tw_kernel<<<72, 256, 0, stream>>>(a1pk, a2pk);
  xt_kernel<<<256, 256, 0, stream>>>(x, xt);

  dft1_kernel<<<256, 256, 0, stream>>>(x, a1pk, F1);
  dft2_kernel<<<256, 256, 0, stream>>>(F1, a2pk, magbuf);
  fe_reduce_kernel<<<144, 256, 0, stream>>>(magbuf, fe);

  aux_conv_kernel<<<1024, 256, 0, stream>>>(xt, fe, apkA, offset_b, gate_b1,
                                            gate_w2, gate_b2, offsb, gatebuf);

  fused_out_kernel<<<1024, 256, 0, stream>>>(xt, offsb, apkF, base_b, def_b,
                                             gatebuf, out);
}